// Round 19
// baseline (29.091 us; speedup 1.0000x reference)
//
#include <hip/hip_runtime.h>

// Gaussian-splat heatmap as a per-image MFMA GEMM — single compute pass with
// hybrid staging (strip1 -> private LDS, strip2 -> registers), 2 blocks/CU,
// amp-free contiguous drain. (vs R17 23.33us: removes the pass-2 recompute.)
//   heat[y][x] = sum_p Rmat[y][p] * CmatT[x][p]   (M=N=200 padded to 224, K=64)
//   Rmat[y][p]  = k1n[y-ys_p] if 0<=y-ys_p<ky_p else 0  (top-left-slice quirk)
//   CmatT[x][p] = k1n[x-xs_p] if 0<=x-xs_p<kx_p else 0
// bf16 LDS rows of 128 B, XOR-swizzled byte ^= ((row&7)<<4) (G4/T2).
// mfma_f32_16x16x32_bf16 (verified R13/R16/R17/R18): A row=lane&15,
// k=8*(lane>>4)+j (+32 second K-half); C/D col=lane&15 (=x), row=4*(lane>>4)+reg.
//
// Structure (one image per block, 512 blocks = 2 blk/CU):
//  build Rm -> cache A-frags -> rebuild M as Cm (sequential single buffer) ->
//  ONE compute pass: strip1 accs -> unnormalized bf16 -> private stage[wv];
//  strip2 accs stay in 52 VGPRs. Max-reduce -> drain strip1 (scale in the
//  bf16->f32 convert; contiguous 128B-aligned full lines) -> restage strip2
//  into the same private area (same-wave LDS ordering, no barrier) -> drain.
// LDS 79.9KB <= 81.9 -> 2 blk/CU; launch_bounds(512,4) caps VGPR at 128.
// R7/R15/R16/R18 lesson: never drop below 2 blk/CU. R16 lesson: compute
// volume is ~free; what matters is when stores ISSUE -> this issues them one
// full compute-pass earlier than R17.
// Falsifier: >=23us -> recompute wasn't critical -> ~23us wall is structural.

#define NT 64
#define TDIM 224
#define BLK 512

typedef short bf16x8 __attribute__((ext_vector_type(8)));
typedef float f32x4  __attribute__((ext_vector_type(4)));

// f32 -> bf16 round-to-nearest-even
static __device__ inline unsigned short f2bf(float f) {
    unsigned int u = __float_as_uint(f);
    u = (u + 0x7FFFu + ((u >> 16) & 1u)) >> 16;
    return (unsigned short)u;
}

struct __align__(16) SMem {
    unsigned short M[TDIM][64];        // 28,672 B: Rm first, then rebuilt as Cm
    unsigned short stg[8][16][200];    // 51,200 B: per-wave private stage
    float k1f[37];
    float wmax[8];
};

__global__ __launch_bounds__(BLK, 4) void heatmap_kernel(const float* __restrict__ x_t,
                                                         float* __restrict__ out) {
    __shared__ SMem s;
    const int tid  = threadIdx.x;
    const int lane = tid & 63;
    const int wv   = tid >> 6;          // 0..7
    const int b    = blockIdx.x;
    const int swl  = (lane & 7) << 4;

    // --- zero M + k1f table ---
    {
        uint4 z = {0u, 0u, 0u, 0u};
        uint4* base = (uint4*)s.M;
        #pragma unroll
        for (int i = 0; i < 4; ++i) {
            const int idx = tid + BLK * i;
            if (idx < 1792) base[idx] = z;
        }
    }
    if (tid < 37) {
        float sum = 0.0f, mine = 0.0f;
        #pragma unroll
        for (int i = 0; i < 37; ++i) {
            float r = (float)(i - 18);
            float v = expf(-(r * r) * (1.0f / 18.0f));   // sigma=3 -> 2*sigma^2=18
            sum += v;
            if (i == tid) mine = v;
        }
        s.k1f[tid] = mine / sum;
    }
    __syncthreads();

    // --- per-point meta: 8 threads per point (replicates reference exactly) ---
    const int p = tid >> 3, j = tid & 7;
    const float2 xy = *(const float2*)(x_t + (size_t)b * 128 + 2 * p);
    const bool valid = (xy.x == xy.x) && (xy.y == xy.y);
    const int xp = (int)(xy.x * 2.0f);                 // trunc == astype(int32), x>=0
    const int yp = 200 - (int)(xy.y * 2.0f);
    const int xs = min(max(xp - 18, 0), 164);
    const int ys = min(max(yp - 18, 0), 164);
    const int kx = valid ? (min(max(xp + 18, 0), 200) - xs) : 0;   // <= 36
    const int ky = valid ? (min(max(yp + 18, 0), 200) - ys) : 0;

    // --- build Rm (rows = y) ---
    #pragma unroll
    for (int i = 0; i < 5; ++i) {
        const int rel = j * 5 + i;                     // 0..39 covers 0..35
        if (rel < ky) {
            const int row = ys + rel;
            *(unsigned short*)((char*)s.M + row * 128 + ((2 * p) ^ ((row & 7) << 4)))
                = f2bf(s.k1f[rel]);
        }
    }
    __syncthreads();

    // --- cache A-frags for this wave's strips (s1 = wv, s2 = wv+8 if < 13) ---
    const int s1 = wv, s2 = wv + 8;
    bf16x8 A10, A11, A20, A21;
    {
        const char* ab = (const char*)s.M + (16 * s1 + (lane & 15)) * 128;
        A10 = *(const bf16x8*)(ab + ((16 * (lane >> 4)) ^ swl));
        A11 = *(const bf16x8*)(ab + ((16 * (lane >> 4) + 64) ^ swl));
    }
    if (s2 < 13) {
        const char* ab = (const char*)s.M + (16 * s2 + (lane & 15)) * 128;
        A20 = *(const bf16x8*)(ab + ((16 * (lane >> 4)) ^ swl));
        A21 = *(const bf16x8*)(ab + ((16 * (lane >> 4) + 64) ^ swl));
    } else { A20 = A10; A21 = A11; }
    __syncthreads();                                   // all A-frag reads done

    // --- re-zero M, rebuild as Cm (rows = x) ---
    {
        uint4 z = {0u, 0u, 0u, 0u};
        uint4* base = (uint4*)s.M;
        #pragma unroll
        for (int i = 0; i < 4; ++i) {
            const int idx = tid + BLK * i;
            if (idx < 1792) base[idx] = z;
        }
    }
    __syncthreads();
    #pragma unroll
    for (int i = 0; i < 5; ++i) {
        const int rel = j * 5 + i;
        if (rel < kx) {
            const int row = xs + rel;
            *(unsigned short*)((char*)s.M + row * 128 + ((2 * p) ^ ((row & 7) << 4)))
                = f2bf(s.k1f[rel]);
        }
    }
    __syncthreads();

    const int r0l = 4 * (lane >> 4), c0l = lane & 15;
    float gmax = 0.0f;

    // --- single compute pass, part 1: strip s1 -> unnormalized bf16 stage ---
    {
        f32x4 acc[13];
        #pragma unroll
        for (int t = 0; t < 13; ++t) {
            acc[t][0] = 0.0f; acc[t][1] = 0.0f; acc[t][2] = 0.0f; acc[t][3] = 0.0f;
        }
        #pragma unroll
        for (int t = 0; t < 13; ++t) {
            const char* bb = (const char*)s.M + (16 * t + (lane & 15)) * 128;
            bf16x8 B0 = *(const bf16x8*)(bb + ((16 * (lane >> 4)) ^ swl));
            bf16x8 B1 = *(const bf16x8*)(bb + ((16 * (lane >> 4) + 64) ^ swl));
            acc[t] = __builtin_amdgcn_mfma_f32_16x16x32_bf16(A10, B0, acc[t], 0, 0, 0);
            acc[t] = __builtin_amdgcn_mfma_f32_16x16x32_bf16(A11, B1, acc[t], 0, 0, 0);
        }
        unsigned short* st = &s.stg[wv][0][0];
        #pragma unroll
        for (int t = 0; t < 13; ++t) {
            const int col = 16 * t + c0l;
            #pragma unroll
            for (int r = 0; r < 4; ++r) gmax = fmaxf(gmax, acc[t][r]);
            if (col < 200) {                           // t=12 cols 200..207: skip
                #pragma unroll
                for (int r = 0; r < 4; ++r)
                    st[(r0l + r) * 200 + col] = f2bf(acc[t][r]);
            }
        }
    }

    // --- part 2: strip s2 -> accs kept in registers (52 VGPR) ---
    f32x4 acc2[13];
    #pragma unroll
    for (int t = 0; t < 13; ++t) {
        acc2[t][0] = 0.0f; acc2[t][1] = 0.0f; acc2[t][2] = 0.0f; acc2[t][3] = 0.0f;
    }
    if (s2 < 13) {
        #pragma unroll
        for (int t = 0; t < 13; ++t) {
            const char* bb = (const char*)s.M + (16 * t + (lane & 15)) * 128;
            bf16x8 B0 = *(const bf16x8*)(bb + ((16 * (lane >> 4)) ^ swl));
            bf16x8 B1 = *(const bf16x8*)(bb + ((16 * (lane >> 4) + 64) ^ swl));
            acc2[t] = __builtin_amdgcn_mfma_f32_16x16x32_bf16(A20, B0, acc2[t], 0, 0, 0);
            acc2[t] = __builtin_amdgcn_mfma_f32_16x16x32_bf16(A21, B1, acc2[t], 0, 0, 0);
        }
        #pragma unroll
        for (int t = 0; t < 13; ++t) {
            #pragma unroll
            for (int r = 0; r < 4; ++r) gmax = fmaxf(gmax, acc2[t][r]);
        }
    }

    // --- block max reduce ---
    #pragma unroll
    for (int off = 32; off > 0; off >>= 1) gmax = fmaxf(gmax, __shfl_xor(gmax, off));
    if (lane == 0) s.wmax[wv] = gmax;
    __syncthreads();
    float mm = s.wmax[0];
    #pragma unroll
    for (int w = 1; w < 8; ++w) mm = fmaxf(mm, s.wmax[w]);
    const float scale = 1.0f / (mm + 1e-10f);

    // --- drain strip s1: contiguous 128B-aligned full-line stores ---
    float* ob = out + (size_t)b * (200 * 200);
    unsigned short* st = &s.stg[wv][0][0];
    {
        float* obs = ob + (size_t)(16 * s1) * 200;
        for (int i = lane; i < 16 * 50; i += 64) {
            uint2 v = *(const uint2*)(st + 4 * i);
            float4 o;
            o.x = __uint_as_float(v.x << 16) * scale;
            o.y = __uint_as_float(v.x & 0xFFFF0000u) * scale;
            o.z = __uint_as_float(v.y << 16) * scale;
            o.w = __uint_as_float(v.y & 0xFFFF0000u) * scale;
            *(float4*)(obs + 4 * i) = o;
        }
    }

    // --- restage strip s2 into the same private area, then drain ---
    // (LDS ops are in-order per wave: these writes execute after the drain
    //  reads above; the stage is per-wave private, so no barrier needed.)
    if (s2 < 13) {
        #pragma unroll
        for (int t = 0; t < 13; ++t) {
            const int col = 16 * t + c0l;
            if (col < 200) {
                #pragma unroll
                for (int r = 0; r < 4; ++r)
                    st[(r0l + r) * 200 + col] = f2bf(acc2[t][r]);
            }
        }
        const int nrow = min(16, 200 - 16 * s2);       // 16, or 8 for strip 12
        float* obs = ob + (size_t)(16 * s2) * 200;
        for (int i = lane; i < nrow * 50; i += 64) {
            uint2 v = *(const uint2*)(st + 4 * i);
            float4 o;
            o.x = __uint_as_float(v.x << 16) * scale;
            o.y = __uint_as_float(v.x & 0xFFFF0000u) * scale;
            o.z = __uint_as_float(v.y << 16) * scale;
            o.w = __uint_as_float(v.y & 0xFFFF0000u) * scale;
            *(float4*)(obs + 4 * i) = o;
        }
    }
}

extern "C" void kernel_launch(void* const* d_in, const int* in_sizes, int n_in,
                              void* d_out, int out_size, void* d_ws, size_t ws_size,
                              hipStream_t stream) {
    const float* x_t = (const float*)d_in[0];
    float* out = (float*)d_out;
    const int B = in_sizes[0] / (NT * 2);   // 512
    heatmap_kernel<<<B, BLK, 0, stream>>>(x_t, out);
}

// Round 20
// 24.769 us; speedup vs baseline: 1.1745x; 1.1745x over previous
//
#include <hip/hip_runtime.h>

// Gaussian-splat heatmap as a per-image MFMA GEMM — R17 (23.33us) + CU-level
// block desynchronization (single-variable change).
//   heat[y][x] = sum_p Rmat[y][p] * CmatT[x][p]   (M=N=200 padded to 224, K=64)
//   Rmat[y][p]  = k1n[y-ys_p] if 0<=y-ys_p<ky_p else 0  (top-left-slice quirk)
//   CmatT[x][p] = k1n[x-xs_p] if 0<=x-xs_p<kx_p else 0
// bf16 LDS rows of 128 B, XOR-swizzled byte ^= ((row&7)<<4) (G4/T2).
// mfma_f32_16x16x32_bf16 (verified R13/R16/R17): A row=lane&15, k=8*(lane>>4)+j
// (+32 second half); C/D col=lane&15 (=x), row=4*(lane>>4)+reg (=y).
//
// Desync rationale: all >=23us variants share lockstep dispatch — both blocks
// on a CU run their HBM-idle prefix together (~5us, contending), then drain
// together. Blocks 256..511 land as the SECOND block on each CU (dispatch
// fills 256 CUs round-robin, then wraps); sleeping them ~3.4us (s_sleep(127))
// lets block-1's prefix run uncontended, overlaps block-1's drain with
// block-2's prefix, and keeps the CU's store stream continuous:
// 3.5 (P1) + 6.3 (D1 || P2) + 6.3 (D2) ~= 16-18us + tail.
// Falsifier: >=23us -> plateau is structural; declare roofline.

#define NT 64
#define TDIM 224
#define BLK 512

typedef short bf16x8 __attribute__((ext_vector_type(8)));
typedef float f32x4  __attribute__((ext_vector_type(4)));

// f32 -> bf16 round-to-nearest-even
static __device__ inline unsigned short f2bf(float f) {
    unsigned int u = __float_as_uint(f);
    u = (u + 0x7FFFu + ((u >> 16) & 1u)) >> 16;
    return (unsigned short)u;
}

struct __align__(16) SMem {
    unsigned short M[TDIM][64];        // 28,672 B: Rm first, then rebuilt as Cm
    unsigned short stg[8][16][200];    // 51,200 B: per-wave private stage
    float k1f[37];
    float wmax[8];
};

__global__ __launch_bounds__(BLK, 4) void heatmap_kernel(const float* __restrict__ x_t,
                                                         float* __restrict__ out) {
    __shared__ SMem s;
    const int tid  = threadIdx.x;
    const int lane = tid & 63;
    const int wv   = tid >> 6;          // 0..7
    const int b    = blockIdx.x;
    const int swl  = (lane & 7) << 4;

    // --- desync: second-round blocks (2nd block on each CU) start ~3.4us late ---
    if (b >= 256) __builtin_amdgcn_s_sleep(127);

    // --- zero M + k1f table ---
    {
        uint4 z = {0u, 0u, 0u, 0u};
        uint4* base = (uint4*)s.M;
        #pragma unroll
        for (int i = 0; i < 4; ++i) {
            const int idx = tid + BLK * i;
            if (idx < 1792) base[idx] = z;
        }
    }
    if (tid < 37) {
        float sum = 0.0f, mine = 0.0f;
        #pragma unroll
        for (int i = 0; i < 37; ++i) {
            float r = (float)(i - 18);
            float v = expf(-(r * r) * (1.0f / 18.0f));   // sigma=3 -> 2*sigma^2=18
            sum += v;
            if (i == tid) mine = v;
        }
        s.k1f[tid] = mine / sum;
    }
    __syncthreads();

    // --- per-point meta: 8 threads per point (replicates reference exactly) ---
    const int p = tid >> 3, j = tid & 7;
    const float2 xy = *(const float2*)(x_t + (size_t)b * 128 + 2 * p);
    const bool valid = (xy.x == xy.x) && (xy.y == xy.y);
    const int xp = (int)(xy.x * 2.0f);                 // trunc == astype(int32), x>=0
    const int yp = 200 - (int)(xy.y * 2.0f);
    const int xs = min(max(xp - 18, 0), 164);
    const int ys = min(max(yp - 18, 0), 164);
    const int kx = valid ? (min(max(xp + 18, 0), 200) - xs) : 0;   // <= 36
    const int ky = valid ? (min(max(yp + 18, 0), 200) - ys) : 0;

    // --- build Rm (rows = y) ---
    #pragma unroll
    for (int i = 0; i < 5; ++i) {
        const int rel = j * 5 + i;                     // 0..39 covers 0..35
        if (rel < ky) {
            const int row = ys + rel;
            *(unsigned short*)((char*)s.M + row * 128 + ((2 * p) ^ ((row & 7) << 4)))
                = f2bf(s.k1f[rel]);
        }
    }
    __syncthreads();

    // --- cache A-frags for this wave's strips (s1 = wv, s2 = wv+8 if < 13) ---
    const int s1 = wv, s2 = wv + 8;
    bf16x8 A10, A11, A20, A21;
    {
        const char* ab = (const char*)s.M + (16 * s1 + (lane & 15)) * 128;
        A10 = *(const bf16x8*)(ab + ((16 * (lane >> 4)) ^ swl));
        A11 = *(const bf16x8*)(ab + ((16 * (lane >> 4) + 64) ^ swl));
    }
    if (s2 < 13) {
        const char* ab = (const char*)s.M + (16 * s2 + (lane & 15)) * 128;
        A20 = *(const bf16x8*)(ab + ((16 * (lane >> 4)) ^ swl));
        A21 = *(const bf16x8*)(ab + ((16 * (lane >> 4) + 64) ^ swl));
    } else { A20 = A10; A21 = A11; }
    __syncthreads();                                   // all A-frag reads done

    // --- re-zero M, rebuild as Cm (rows = x) ---
    {
        uint4 z = {0u, 0u, 0u, 0u};
        uint4* base = (uint4*)s.M;
        #pragma unroll
        for (int i = 0; i < 4; ++i) {
            const int idx = tid + BLK * i;
            if (idx < 1792) base[idx] = z;
        }
    }
    __syncthreads();
    #pragma unroll
    for (int i = 0; i < 5; ++i) {
        const int rel = j * 5 + i;
        if (rel < kx) {
            const int row = xs + rel;
            *(unsigned short*)((char*)s.M + row * 128 + ((2 * p) ^ ((row & 7) << 4)))
                = f2bf(s.k1f[rel]);
        }
    }
    __syncthreads();

    // --- strip compute helper: 13 col-tiles, K=64 as two 16x16x32 MFMAs ---
    auto compute_strip = [&](bf16x8 A0, bf16x8 A1, f32x4* acc) {
        #pragma unroll
        for (int t = 0; t < 13; ++t) {
            acc[t][0] = 0.0f; acc[t][1] = 0.0f; acc[t][2] = 0.0f; acc[t][3] = 0.0f;
        }
        #pragma unroll
        for (int t = 0; t < 13; ++t) {
            const char* bb = (const char*)s.M + (16 * t + (lane & 15)) * 128;
            bf16x8 B0 = *(const bf16x8*)(bb + ((16 * (lane >> 4)) ^ swl));
            bf16x8 B1 = *(const bf16x8*)(bb + ((16 * (lane >> 4) + 64) ^ swl));
            acc[t] = __builtin_amdgcn_mfma_f32_16x16x32_bf16(A0, B0, acc[t], 0, 0, 0);
            acc[t] = __builtin_amdgcn_mfma_f32_16x16x32_bf16(A1, B1, acc[t], 0, 0, 0);
        }
    };

    // --- pass 1: max (pad rows/cols >=200 are exact zeros -> unguarded max ok) ---
    float gmax = 0.0f;
    {
        f32x4 acc[13];
        compute_strip(A10, A11, acc);
        #pragma unroll
        for (int t = 0; t < 13; ++t)
            #pragma unroll
            for (int r = 0; r < 4; ++r) gmax = fmaxf(gmax, acc[t][r]);
        if (s2 < 13) {
            compute_strip(A20, A21, acc);
            #pragma unroll
            for (int t = 0; t < 13; ++t)
                #pragma unroll
                for (int r = 0; r < 4; ++r) gmax = fmaxf(gmax, acc[t][r]);
        }
    }
    #pragma unroll
    for (int off = 32; off > 0; off >>= 1) gmax = fmaxf(gmax, __shfl_xor(gmax, off));
    if (lane == 0) s.wmax[wv] = gmax;
    __syncthreads();
    float mm = s.wmax[0];
    #pragma unroll
    for (int w = 1; w < 8; ++w) mm = fmaxf(mm, s.wmax[w]);
    const float scale = 1.0f / (mm + 1e-10f);

    // --- pass 2: recompute strip -> private stage (scaled bf16) -> contiguous
    //     drain. No barriers; draining waves overlap computing ones.
    float* ob = out + (size_t)b * (200 * 200);
    unsigned short* st = &s.stg[wv][0][0];
    auto do_strip = [&](int ss, bf16x8 A0, bf16x8 A1) {
        f32x4 acc[13];
        compute_strip(A0, A1, acc);
        const int r0l = 4 * (lane >> 4), c0l = lane & 15;
        #pragma unroll
        for (int t = 0; t < 13; ++t) {
            const int col = 16 * t + c0l;
            if (col < 200) {                      // t=12 cols 200..207 would OOB
                #pragma unroll
                for (int r = 0; r < 4; ++r)
                    st[(r0l + r) * 200 + col] = f2bf(acc[t][r] * scale);
            }
        }
        __threadfence_block();                    // order stage writes before reads
        const int nrow = min(16, 200 - 16 * ss);  // 16, or 8 for strip 12
        float* obs = ob + (size_t)(16 * ss) * 200;
        for (int i = lane; i < nrow * 50; i += 64) {
            uint2 v = *(const uint2*)(st + 4 * i);
            float4 o;
            o.x = __uint_as_float(v.x << 16);
            o.y = __uint_as_float(v.x & 0xFFFF0000u);
            o.z = __uint_as_float(v.y << 16);
            o.w = __uint_as_float(v.y & 0xFFFF0000u);
            *(float4*)(obs + 4 * i) = o;          // contiguous, 128B-aligned, full lines
        }
    };
    do_strip(s1, A10, A11);
    if (s2 < 13) do_strip(s2, A20, A21);
}

extern "C" void kernel_launch(void* const* d_in, const int* in_sizes, int n_in,
                              void* d_out, int out_size, void* d_ws, size_t ws_size,
                              hipStream_t stream) {
    const float* x_t = (const float*)d_in[0];
    float* out = (float*)d_out;
    const int B = in_sizes[0] / (NT * 2);   // 512
    heatmap_kernel<<<B, BLK, 0, stream>>>(x_t, out);
}